// Round 2
// baseline (2631.366 us; speedup 1.0000x reference)
//
#include <hip/hip_runtime.h>
#include <cfloat>

// Problem constants: inputs (64,256,512) fp32, emb (1024,512) fp32.
#define NROWS  16384          // 64*256
#define DIM    512
#define KC     1024
#define QELEMS (NROWS * DIM)  // 8388608
// d_out layout (fp32): [0]=loss, [1 .. QELEMS]=quantized, [1+QELEMS .. +NROWS]=indices (as float)

#define BM   128              // rows per block tile
#define BD   32               // D-chunk
#define LDST 36               // padded LDS row stride: 144 B = 16B-aligned

// ---------------- kernel 1: row sums of squares (used for E and for A) ----------------
// one wave per row; grid*4 rows total
__global__ __launch_bounds__(256) void rowsq_kernel(const float* __restrict__ M,
                                                    float* __restrict__ out) {
    int wave = threadIdx.x >> 6, lane = threadIdx.x & 63;
    int row = blockIdx.x * 4 + wave;
    const float4* Mr = (const float4*)(M + (size_t)row * DIM);
    float s = 0.f;
    #pragma unroll
    for (int i = 0; i < 2; ++i) {                 // 128 float4 / 64 lanes
        float4 v = Mr[lane + 64 * i];
        s += v.x*v.x + v.y*v.y + v.z*v.z + v.w*v.w;
    }
    #pragma unroll
    for (int off = 32; off; off >>= 1) s += __shfl_down(s, off, 64);
    if (lane == 0) out[row] = s;
}

// ---------------- kernel 2: fused distance GEMM + argmin ----------------
// grid = 256 blocks: blockIdx>>1 = row tile (128 rows), blockIdx&1 = K-split (512 codes).
// Replicates the fp32 reference expression EXACTLY per entry:
//   d = fl( fl(sqx_n + sqe_k) - 2*m_nk )
// The +||x||^2 term (magnitude ~512, ulp 6.1e-5) quantizes the distances the same
// way numpy's fp32 evaluation does — required to match its argmin decisions.
__global__ __launch_bounds__(256) void argmin_kernel(const float* __restrict__ A,
                                                     const float* __restrict__ E,
                                                     const float* __restrict__ esq,
                                                     const float* __restrict__ xsq,
                                                     float* __restrict__ vals,
                                                     int* __restrict__ idxs) {
    __shared__ float As[BM][LDST];
    __shared__ float Es[BM][LDST];
    const int tid = threadIdx.x;
    const int tx = tid & 15, ty = tid >> 4;       // 16x16 thread grid
    const int m0 = (blockIdx.x >> 1) * BM;
    const int split = blockIdx.x & 1;
    const int c0 = split * (KC / 2);

    float sqx8[8];
    #pragma unroll
    for (int i = 0; i < 8; ++i) sqx8[i] = xsq[m0 + i*16 + ty];

    float bv[8]; int bi[8];
    #pragma unroll
    for (int i = 0; i < 8; ++i) { bv[i] = FLT_MAX; bi[i] = 0x7fffffff; }

    for (int ct = 0; ct < 4; ++ct) {              // 4 code tiles of 128 per split
        const int cc = c0 + ct * BM;
        float acc[8][8];
        #pragma unroll
        for (int i = 0; i < 8; ++i)
            #pragma unroll
            for (int j = 0; j < 8; ++j) acc[i][j] = 0.f;

        for (int dch = 0; dch < DIM / BD; ++dch) {
            const int dbase = dch * BD;
            #pragma unroll
            for (int q = 0; q < 4; ++q) {
                int f = tid * 4 + q;              // 0..1023
                int row = f >> 3;
                int c4  = (f & 7) * 4;
                *(float4*)&As[row][c4] =
                    *(const float4*)(A + (size_t)(m0 + row) * DIM + dbase + c4);
                *(float4*)&Es[row][c4] =
                    *(const float4*)(E + (size_t)(cc + row) * DIM + dbase + c4);
            }
            __syncthreads();
            #pragma unroll
            for (int d4 = 0; d4 < BD / 4; ++d4) {
                float4 a4[8], b4[8];
                #pragma unroll
                for (int i = 0; i < 8; ++i) a4[i] = *(const float4*)&As[i*16 + ty][d4*4];
                #pragma unroll
                for (int j = 0; j < 8; ++j) b4[j] = *(const float4*)&Es[j*16 + tx][d4*4];
                #pragma unroll
                for (int i = 0; i < 8; ++i)
                    #pragma unroll
                    for (int j = 0; j < 8; ++j)
                        acc[i][j] += a4[i].x*b4[j].x + a4[i].y*b4[j].y
                                   + a4[i].z*b4[j].z + a4[i].w*b4[j].w;
            }
            __syncthreads();
        }

        // scores + argmin for this 128-code tile
        float esv[8];
        #pragma unroll
        for (int j = 0; j < 8; ++j) esv[j] = esq[cc + j*16 + tx];
        #pragma unroll
        for (int i = 0; i < 8; ++i) {
            float v = FLT_MAX; int ci = 0x7fffffff;
            #pragma unroll
            for (int j = 0; j < 8; ++j) {
                // two-step fp32 rounding, matching numpy's (sqx+sqe) - 2*M
                float S = sqx8[i] + esv[j];       // fl(sqx + sqe): separate rounding
                float s = S - 2.0f * acc[i][j];   // fl(S - 2m); 2m exact
                int   c = cc + j*16 + tx;
                if (s < v || (s == v && c < ci)) { v = s; ci = c; }
            }
            #pragma unroll
            for (int m = 1; m < 16; m <<= 1) {
                float ov = __shfl_xor(v, m, 64);
                int   oc = __shfl_xor(ci, m, 64);
                if (ov < v || (ov == v && oc < ci)) { v = ov; ci = oc; }
            }
            if (v < bv[i] || (v == bv[i] && ci < bi[i])) { bv[i] = v; bi[i] = ci; }
        }
    }

    if (tx == 0) {
        #pragma unroll
        for (int i = 0; i < 8; ++i) {
            int n = m0 + i*16 + ty;
            vals[split * NROWS + n] = bv[i];
            idxs[split * NROWS + n] = bi[i];
        }
    }
}

// ---------------- kernel 3: merge K-splits, emit indices, zero loss ----------------
__global__ __launch_bounds__(256) void combine_kernel(const float* __restrict__ vals,
                                                      const int* __restrict__ idxs,
                                                      float* __restrict__ out) {
    int n = blockIdx.x * 256 + threadIdx.x;       // grid=64 -> 16384
    if (n == 0) out[0] = 0.f;
    float v0 = vals[n], v1 = vals[NROWS + n];
    int   i0 = idxs[n], i1 = idxs[NROWS + n];
    int idx = (v1 < v0) ? i1 : i0;                // tie -> split 0 (smaller index)
    out[1 + QELEMS + n] = (float)idx;
}

// ---------------- kernel 4: gather quantized + loss ----------------
__global__ __launch_bounds__(256) void gather_loss_kernel(const float* __restrict__ A,
                                                          const float* __restrict__ E,
                                                          float* __restrict__ out) {
    const float* idxF = out + 1 + QELEMS;
    float* q = out + 1;
    int t = threadIdx.x;
    int row = blockIdx.x * 2 + (t >> 7);          // grid=8192, 2 rows/block
    int d4  = (t & 127) * 4;
    int idx = (int)idxF[row];
    float4 e = *(const float4*)(E + (size_t)idx * DIM + d4);
    float4 x = *(const float4*)(A + (size_t)row * DIM + d4);
    *(float4*)(q + (size_t)row * DIM + d4) = e;
    float d0 = e.x - x.x, d1 = e.y - x.y, d2 = e.z - x.z, d3 = e.w - x.w;
    float s = d0*d0 + d1*d1 + d2*d2 + d3*d3;
    #pragma unroll
    for (int off = 32; off; off >>= 1) s += __shfl_down(s, off, 64);
    __shared__ float ps[4];
    if ((t & 63) == 0) ps[t >> 6] = s;
    __syncthreads();
    if (t == 0)
        atomicAdd(out, (ps[0] + ps[1] + ps[2] + ps[3]) * (1.25f / (float)QELEMS));
}

extern "C" void kernel_launch(void* const* d_in, const int* in_sizes, int n_in,
                              void* d_out, int out_size, void* d_ws, size_t ws_size,
                              hipStream_t stream) {
    const float* A = (const float*)d_in[0];   // inputs (64,256,512)
    const float* E = (const float*)d_in[1];   // emb_weight (1024,512)
    float* out = (float*)d_out;

    float* esq  = (float*)d_ws;               // 1024 floats
    float* xsq  = esq + KC;                   // 16384 floats
    float* vals = xsq + NROWS;                // 2*16384 floats
    int*   idxs = (int*)(vals + 2 * NROWS);   // 2*16384 ints

    rowsq_kernel<<<KC / 4,    256, 0, stream>>>(E, esq);
    rowsq_kernel<<<NROWS / 4, 256, 0, stream>>>(A, xsq);
    argmin_kernel<<<(NROWS / BM) * 2, 256, 0, stream>>>(A, E, esq, xsq, vals, idxs);
    combine_kernel<<<NROWS / 256, 256, 0, stream>>>(vals, idxs, out);
    gather_loss_kernel<<<NROWS / 2, 256, 0, stream>>>(A, E, out);
}